// Round 19
// baseline (192.410 us; speedup 1.0000x reference)
//
#include <hip/hip_runtime.h>

// LOCKED-IN KERNEL: all-fp32 fused two-layer GRU (Round-5 configuration).
// Bench: 192.7 us, absmax 0.0 (fp32 everywhere -> ~1e-6 true error, 4 orders
// of magnitude below the 6.21e-3 threshold; immune to codegen drift).
// Rationale: every f16-recurrence variant (R13/R14, 150-183 us) lands at
// absmax 5.9-6.2e-3 vs threshold 6.21e-3 and fails nondeterministically
// across recompiles (R18: same source, absmax 6.10e-3 -> 6.23e-3). All
// accuracy-robust alternatives measured are slower than this kernel.

static constexpr int T_LEN = 512;

typedef float v2f __attribute__((ext_vector_type(2)));

__device__ __forceinline__ float fsigm(float x) {
    return __builtin_amdgcn_rcpf(1.0f + __expf(-x));
}
__device__ __forceinline__ float ftanh(float x) {
    return 1.0f - 2.0f * __builtin_amdgcn_rcpf(1.0f + __expf(2.0f * x));
}
template <int CTRL>
__device__ __forceinline__ float rotf(float v) {
    return __builtin_bit_cast(float,
        __builtin_amdgcn_mov_dpp(__builtin_bit_cast(int, v), CTRL, 0xf, 0xf, true));
}
// rotate both halves of a packed pair by 2 lanes within the 16-lane row
__device__ __forceinline__ v2f rot2(v2f p) {
    v2f r;
    r.x = rotf<0x122>(p.x);
    r.y = rotf<0x122>(p.y);
    return r;
}

// Block = 4 waves, 8 batches. Waves 0,1: layer-0; waves 2,3: layer-1 one
// 4-step group behind. h distributed 1 unit/lane; ALL matvecs are DPP-rotation
// systolic with rotation-permuted weights, expressed as packed f32 pairs
// (v_pk_fma_f32). x is lane-distributed (2 VGPR/step). Barrier = s_waitcnt
// lgkmcnt(0) + s_barrier only, once per 4 steps; global prefetches stay in
// flight across it.
__global__ __launch_bounds__(256, 1) void gru2_pipe(
    const float* __restrict__ x,
    const float* __restrict__ Wih0, const float* __restrict__ Whh0,
    const float* __restrict__ bih0, const float* __restrict__ bhh0,
    const float* __restrict__ Wih1, const float* __restrict__ Whh1,
    const float* __restrict__ bih1, const float* __restrict__ bhh1,
    const float* __restrict__ fcw,  const float* __restrict__ fcb,
    float* __restrict__ out)
{
    const int tid  = threadIdx.x;
    const int w    = tid >> 6;                    // wave in block (0..3)
    const int lane = tid & 63;
    const int j    = lane & 15;                   // unit index
    const int bb   = (w & 1) * 4 + (lane >> 4);   // batch within block (0..7)
    const int b    = blockIdx.x * 8 + bb;
    const bool isL0 = (w < 2);

    __shared__ float h0buf[8][8][16];   // 4 KB ring: [step&7][bb][unit]

    // rotation-direction probes (robust to ror encoding/direction)
    const int d1 = (((int)rotf<0x121>((float)j)) - j) & 15;  // shift of ror:1
    const int d2 = (((int)rotf<0x122>((float)j)) - j) & 15;  // shift of ror:2

    // ---- packed weights, one array for both roles ----
    // L0: W[g][k]     = (Whh0[row, c(2k)],    Whh0[row, c(2k+1)])      k=0..7
    //     W[g][8+k]   = (Wih0[row, c(2k)],    Wih0[row, c(2k+1)])
    //     W[g][16+k]  = (Wih0[row, 16+c(2k)], Wih0[row, 16+c(2k+1)])
    //     where c(2k)=(j+k*d2)&15, c(2k+1)=(j+d1+k*d2)&15
    // L1: W[g][m]     = (Wih1[row, cm], Whh1[row, cm]), cm=(j+m*d1)&15, m=0..15
    v2f W[3][24];
    float b_r, b_z, b_in, b_hn;

    if (isL0) {
#pragma unroll
        for (int g = 0; g < 3; ++g) {
            const int row = g * 16 + j;
#pragma unroll
            for (int k = 0; k < 8; ++k) {
                const int c0 = (j + k * d2) & 15;
                const int c1 = (j + d1 + k * d2) & 15;
                W[g][k].x      = Whh0[row * 16 + c0];
                W[g][k].y      = Whh0[row * 16 + c1];
                W[g][8 + k].x  = Wih0[row * 32 + c0];
                W[g][8 + k].y  = Wih0[row * 32 + c1];
                W[g][16 + k].x = Wih0[row * 32 + 16 + c0];
                W[g][16 + k].y = Wih0[row * 32 + 16 + c1];
            }
        }
        b_r  = bih0[j]      + bhh0[j];
        b_z  = bih0[16 + j] + bhh0[16 + j];
        b_in = bih0[32 + j];
        b_hn = bhh0[32 + j];
    } else {
#pragma unroll
        for (int g = 0; g < 3; ++g) {
            const int row = g * 16 + j;
#pragma unroll
            for (int m = 0; m < 16; ++m) {
                const int cm = (j + m * d1) & 15;
                W[g][m].x = Wih1[row * 16 + cm];
                W[g][m].y = Whh1[row * 16 + cm];
            }
        }
        b_r  = bih1[j]      + bhh1[j];
        b_z  = bih1[16 + j] + bhh1[16 + j];
        b_in = bih1[32 + j];
        b_hn = bhh1[32 + j];
    }

    float hs = 0.f;   // L0: h0_j ; L1: h1_j (distributed state)

    const float* xbase = x + (size_t)b * T_LEN * 32;

    // ---- 4-step x ring, lane-distributed: 2 VGPR per step ----
    float xl0, xl1, xl2, xl3, xh0, xh1, xh2, xh3;
    if (isL0) {
        xl0 = xbase[0 * 32 + j];  xh0 = xbase[0 * 32 + 16 + j];
        xl1 = xbase[1 * 32 + j];  xh1 = xbase[1 * 32 + 16 + j];
        xl2 = xbase[2 * 32 + j];  xh2 = xbase[2 * 32 + 16 + j];
        xl3 = xbase[3 * 32 + j];  xh3 = xbase[3 * 32 + 16 + j];
    }

    auto l0_step = [&](float& lo, float& hi, int i) {
        const float x0 = lo, x1 = hi;
        // prefetch step i+4 into the just-freed slot (stays in flight
        // across the group barrier — only lgkmcnt is drained there)
        const int t4 = (i + 4 < T_LEN) ? (i + 4) : (T_LEN - 1);
        lo = xbase[t4 * 32 + j];
        hi = xbase[t4 * 32 + 16 + j];

        v2f ptt, px0, px1;
        ptt.x = hs;  ptt.y = rotf<0x121>(hs);
        px0.x = x0;  px0.y = rotf<0x121>(x0);
        px1.x = x1;  px1.y = rotf<0x121>(x1);
        v2f ar = {0.f, 0.f}, az = {0.f, 0.f};
        v2f axn = {0.f, 0.f}, aan = {0.f, 0.f};
#pragma unroll
        for (int k = 0; k < 8; ++k) {
            ar  = __builtin_elementwise_fma(W[0][8 + k],  px0, ar);
            az  = __builtin_elementwise_fma(W[1][8 + k],  px0, az);
            axn = __builtin_elementwise_fma(W[2][8 + k],  px0, axn);
            ar  = __builtin_elementwise_fma(W[0][16 + k], px1, ar);
            az  = __builtin_elementwise_fma(W[1][16 + k], px1, az);
            axn = __builtin_elementwise_fma(W[2][16 + k], px1, axn);
            ar  = __builtin_elementwise_fma(W[0][k], ptt, ar);
            az  = __builtin_elementwise_fma(W[1][k], ptt, az);
            aan = __builtin_elementwise_fma(W[2][k], ptt, aan);
            if (k < 7) { ptt = rot2(ptt); px0 = rot2(px0); px1 = rot2(px1); }
        }
        const float r = fsigm(ar.x + ar.y + b_r);
        const float z = fsigm(az.x + az.y + b_z);
        const float n = ftanh(axn.x + axn.y + b_in + r * (aan.x + aan.y + b_hn));
        hs = fmaf(z, hs - n, n);
        h0buf[i & 7][bb][j] = hs;
    };

    auto l1_step = [&](float u) {
        v2f puv;
        puv.x = u;   // h0[t] contribution (W_ih1 side)
        puv.y = hs;  // h1[t-1] contribution (W_hh1 side)
        v2f ar = {0.f, 0.f}, az = {0.f, 0.f}, an2 = {0.f, 0.f};
#pragma unroll
        for (int m = 0; m < 16; ++m) {
            ar  = __builtin_elementwise_fma(W[0][m], puv, ar);
            az  = __builtin_elementwise_fma(W[1][m], puv, az);
            an2 = __builtin_elementwise_fma(W[2][m], puv, an2);
            if (m < 15) {
                puv.x = rotf<0x121>(puv.x);
                puv.y = rotf<0x121>(puv.y);
            }
        }
        const float r = fsigm(ar.x + ar.y + b_r);
        const float z = fsigm(az.x + az.y + b_z);
        const float n = ftanh(an2.x + b_in + r * (an2.y + b_hn));
        hs = fmaf(z, hs - n, n);
    };

    // ---- grouped pipelined loop: L0 does group g, L1 does group g-1,
    // one lgkm-only barrier per group ----
#pragma unroll 1
    for (int g = 0; g < 129; ++g) {
        if (isL0) {
            if (g < 128) {
                const int s0 = 4 * g;
                l0_step(xl0, xh0, s0);
                l0_step(xl1, xh1, s0 + 1);
                l0_step(xl2, xh2, s0 + 2);
                l0_step(xl3, xh3, s0 + 3);
            }
        } else {
            if (g > 0) {
                const int s0 = 4 * (g - 1);
                // batch the 4 LDS reads so their lgkm waits amortize
                const float u0 = h0buf[(s0 + 0) & 7][bb][j];
                const float u1 = h0buf[(s0 + 1) & 7][bb][j];
                const float u2 = h0buf[(s0 + 2) & 7][bb][j];
                const float u3 = h0buf[(s0 + 3) & 7][bb][j];
                l1_step(u0);
                l1_step(u1);
                l1_step(u2);
                l1_step(u3);
            }
        }
        // LDS-visibility barrier WITHOUT vmcnt drain: x prefetches live on.
        asm volatile("s_waitcnt lgkmcnt(0)\n\ts_barrier" ::: "memory");
    }

    // ---- FC on final h1 (L1 waves hold it distributed) ----
    if (!isL0) {
        float p = fcw[j] * hs;
        p += __shfl_xor(p, 1);
        p += __shfl_xor(p, 2);
        p += __shfl_xor(p, 4);
        p += __shfl_xor(p, 8);
        if (j == 0) out[b] = p + fcb[0];
    }
}

extern "C" void kernel_launch(void* const* d_in, const int* in_sizes, int n_in,
                              void* d_out, int out_size, void* d_ws, size_t ws_size,
                              hipStream_t stream) {
    const float* x    = (const float*)d_in[0];
    const float* Wih0 = (const float*)d_in[1];
    const float* Whh0 = (const float*)d_in[2];
    const float* bih0 = (const float*)d_in[3];
    const float* bhh0 = (const float*)d_in[4];
    const float* Wih1 = (const float*)d_in[5];
    const float* Whh1 = (const float*)d_in[6];
    const float* bih1 = (const float*)d_in[7];
    const float* bhh1 = (const float*)d_in[8];
    const float* fcw  = (const float*)d_in[9];
    const float* fcb  = (const float*)d_in[10];

    // 2048 batches, 8 per block -> 256 blocks x 256 threads (1 block/CU)
    gru2_pipe<<<256, 256, 0, stream>>>(x, Wih0, Whh0, bih0, bhh0,
                                       Wih1, Whh1, bih1, bhh1, fcw, fcb,
                                       (float*)d_out);
}

// Round 20
// 150.732 us; speedup vs baseline: 1.2765x; 1.2765x over previous
//
#include <hip/hip_runtime.h>

static constexpr int T_LEN = 512;

typedef float v2f __attribute__((ext_vector_type(2)));

__device__ __forceinline__ float fsigm(float x) {
    return __builtin_amdgcn_rcpf(1.0f + __expf(-x));
}
__device__ __forceinline__ float ftanh(float x) {
    return 1.0f - 2.0f * __builtin_amdgcn_rcpf(1.0f + __expf(2.0f * x));
}
template <int CTRL>
__device__ __forceinline__ float rotf(float v) {
    return __builtin_bit_cast(float,
        __builtin_amdgcn_mov_dpp(__builtin_bit_cast(int, v), CTRL, 0xf, 0xf, true));
}
template <int CTRL>
__device__ __forceinline__ unsigned rotu(unsigned v) {
    return (unsigned)__builtin_amdgcn_mov_dpp((int)v, CTRL, 0xf, 0xf, true);
}
// f16 pack (x-side ONLY; RTZ, the exact profile R7/R9/R11 passed with)
__device__ __forceinline__ unsigned pk2(float a, float b) {
    return __builtin_bit_cast(unsigned, __builtin_amdgcn_cvt_pkrtz(a, b));
}
__device__ __forceinline__ float dot2(float acc, unsigned w, unsigned p) {
    asm("v_dot2_f32_f16 %0, %1, %2, %0" : "+v"(acc) : "v"(w), "v"(p));
    return acc;
}

// MIXED-PRECISION balanced GRU: R14's exact structure (balance + 8-step
// groups, twice-validated control flow), but ALL h-recurrence dots in fp32
// v_pk_fma (no compounding f16 error); f16 only on x-dots (one-time input
// quantization — R7/R9/R11-proven profile, absmax 1-2e-3, 3x margin).
// Block = 4 waves, 8 batches. Waves 0,1: layer-0; waves 2,3: layer-1 one
// 8-step group behind (h0 via 16-slot fp32 LDS ring, lgkm-only barrier per
// group). Rows 8G+6,8G+7's x-dots computed by L1 waves one group ahead
// (fp32 sums via xgbuf).
__global__ __launch_bounds__(256, 1) void gru2_mix(
    const float* __restrict__ x,
    const float* __restrict__ Wih0, const float* __restrict__ Whh0,
    const float* __restrict__ bih0, const float* __restrict__ bhh0,
    const float* __restrict__ Wih1, const float* __restrict__ Whh1,
    const float* __restrict__ bih1, const float* __restrict__ bhh1,
    const float* __restrict__ fcw,  const float* __restrict__ fcb,
    float* __restrict__ out)
{
    const int tid  = threadIdx.x;
    const int w    = tid >> 6;
    const int lane = tid & 63;
    const int j    = lane & 15;
    const int bb   = (w & 1) * 4 + (lane >> 4);
    const int b    = blockIdx.x * 8 + bb;
    const bool isL0 = (w < 2);

    __shared__ float h0buf[16][8][16];        // 8 KB: [row&15][bb][j]
    __shared__ float xgbuf[2][2][3][8][16];   // 6 KB: [Gpar][row&1][gate][bb][j]

    const int d1 = (((int)rotf<0x121>((float)j)) - j) & 15;
    const float* xbase = x + (size_t)b * T_LEN * 32;

    if (isL0) {
        // ================= layer-0 waves =================
        unsigned WX[3][16];   // f16 pairs (Wih0[row][c], Wih0[row][16+c])
        v2f WHv[3][8];        // fp32 pairs (Whh0[row][c], Whh0[row][(c+8)&15])
#pragma unroll
        for (int g = 0; g < 3; ++g) {
            const int row = g * 16 + j;
#pragma unroll
            for (int m = 0; m < 16; ++m) {
                const int c = (j + m * d1) & 15;
                WX[g][m] = pk2(Wih0[row * 32 + c], Wih0[row * 32 + 16 + c]);
            }
#pragma unroll
            for (int m = 0; m < 8; ++m) {
                const int c = (j + m * d1) & 15;
                WHv[g][m].x = Whh0[row * 16 + c];
                WHv[g][m].y = Whh0[row * 16 + ((c + 8) & 15)];
            }
        }
        const float B_r  = bih0[j]      + bhh0[j];
        const float B_z  = bih0[16 + j] + bhh0[16 + j];
        const float B_in = bih0[32 + j];
        const float B_hn = bhh0[32 + j];

        float hs = 0.f;

        float xa0 = xbase[0*32+j], xh0 = xbase[0*32+16+j];
        float xa1 = xbase[1*32+j], xh1 = xbase[1*32+16+j];
        float xa2 = xbase[2*32+j], xh2 = xbase[2*32+16+j];
        float xa3 = xbase[3*32+j], xh3 = xbase[3*32+16+j];
        float xa4 = xbase[4*32+j], xh4 = xbase[4*32+16+j];
        float xa5 = xbase[5*32+j], xh5 = xbase[5*32+16+j];
        float xa6 = xbase[6*32+j], xh6 = xbase[6*32+16+j];
        float xa7 = xbase[7*32+j], xh7 = xbase[7*32+16+j];

        // fp32 h-dot shared by heavy/light: returns gate values via refs
        auto hdot = [&](float& arh, float& azh, float& anh) {
            v2f qv; qv.x = hs; qv.y = rotf<0x128>(hs);
            v2f ra = {0.f, 0.f}, za = {0.f, 0.f}, na = {0.f, 0.f};
#pragma unroll
            for (int m = 0; m < 8; ++m) {
                ra = __builtin_elementwise_fma(WHv[0][m], qv, ra);
                za = __builtin_elementwise_fma(WHv[1][m], qv, za);
                na = __builtin_elementwise_fma(WHv[2][m], qv, na);
                if (m < 7) { qv.x = rotf<0x121>(qv.x); qv.y = rotf<0x121>(qv.y); }
            }
            arh = ra.x + ra.y;
            azh = za.x + za.y;
            anh = na.x + na.y;
        };

        auto heavy = [&](float& xa, float& xh, int row) {
            unsigned p = pk2(xa, xh);
            int pr = row + 8; if (pr > T_LEN - 1) pr = T_LEN - 1;
            xa = xbase[pr * 32 + j];
            xh = xbase[pr * 32 + 16 + j];
            float ar = B_r, az = B_z, an = B_in;   // f16 x-dot (one-time quant)
#pragma unroll
            for (int m = 0; m < 16; ++m) {
                ar = dot2(ar, WX[0][m], p);
                az = dot2(az, WX[1][m], p);
                an = dot2(an, WX[2][m], p);
                if (m < 15) p = rotu<0x121>(p);
            }
            float arh, azh, anh;
            hdot(arh, azh, anh);
            const float r = fsigm(ar + arh);
            const float z = fsigm(az + azh);
            const float n = ftanh(an + r * (anh + B_hn));
            hs = fmaf(z, hs - n, n);
            h0buf[row & 15][bb][j] = hs;
        };
        auto light = [&](int row) {   // x-part precomputed by L1 waves (fp32)
            const int par = (row >> 3) & 1, rb = row & 1;
            const float ar = xgbuf[par][rb][0][bb][j];
            const float az = xgbuf[par][rb][1][bb][j];
            const float an = xgbuf[par][rb][2][bb][j];
            float arh, azh, anh;
            hdot(arh, azh, anh);
            const float r = fsigm(ar + arh);
            const float z = fsigm(az + azh);
            const float n = ftanh(an + r * (anh + B_hn));
            hs = fmaf(z, hs - n, n);
            h0buf[row & 15][bb][j] = hs;
        };

        // G = 0: all 8 rows heavy (no precomputed xg yet)
        heavy(xa0, xh0, 0); heavy(xa1, xh1, 1); heavy(xa2, xh2, 2);
        heavy(xa3, xh3, 3); heavy(xa4, xh4, 4); heavy(xa5, xh5, 5);
        heavy(xa6, xh6, 6); heavy(xa7, xh7, 7);
        asm volatile("s_waitcnt lgkmcnt(0)\n\ts_barrier" ::: "memory");

#pragma unroll 1
        for (int G = 1; G < 64; ++G) {
            const int r0 = 8 * G;
            heavy(xa0, xh0, r0 + 0);
            heavy(xa1, xh1, r0 + 1);
            heavy(xa2, xh2, r0 + 2);
            heavy(xa3, xh3, r0 + 3);
            heavy(xa4, xh4, r0 + 4);
            heavy(xa5, xh5, r0 + 5);
            light(r0 + 6);
            light(r0 + 7);
            asm volatile("s_waitcnt lgkmcnt(0)\n\ts_barrier" ::: "memory");
        }
        // G = 64: L0 idle, match barrier count
        asm volatile("s_waitcnt lgkmcnt(0)\n\ts_barrier" ::: "memory");
    } else {
        // ================= layer-1 waves =================
        v2f WIv[3][8], WHrv[3][8];   // fp32 pairs (.,c / .,c+8)
        unsigned WX[3][16];          // f16 pairs for transferred x-dots
#pragma unroll
        for (int g = 0; g < 3; ++g) {
            const int row = g * 16 + j;
#pragma unroll
            for (int m = 0; m < 8; ++m) {
                const int c  = (j + m * d1) & 15;
                const int c8 = (c + 8) & 15;
                WIv[g][m].x  = Wih1[row * 16 + c];
                WIv[g][m].y  = Wih1[row * 16 + c8];
                WHrv[g][m].x = Whh1[row * 16 + c];
                WHrv[g][m].y = Whh1[row * 16 + c8];
            }
#pragma unroll
            for (int m = 0; m < 16; ++m) {
                const int c = (j + m * d1) & 15;
                WX[g][m] = pk2(Wih0[row * 32 + c], Wih0[row * 32 + 16 + c]);
            }
        }
        const float B_r  = bih1[j]      + bhh1[j];
        const float B_z  = bih1[16 + j] + bhh1[16 + j];
        const float B_in = bih1[32 + j];
        const float B_hn = bhh1[32 + j];
        const float BX_r = bih0[j]      + bhh0[j];
        const float BX_z = bih0[16 + j] + bhh0[16 + j];
        const float BX_n = bih0[32 + j];

        float hs = 0.f;

        // x ring for transferred rows: current pair = rows 8(G+1)+{6,7}
        float ya0 = xbase[14 * 32 + j], yh0 = xbase[14 * 32 + 16 + j];
        float ya1 = xbase[15 * 32 + j], yh1 = xbase[15 * 32 + 16 + j];

        auto l1_step = [&](float u) {
            v2f p0; p0.x = u;  p0.y = rotf<0x128>(u);
            v2f p1; p1.x = hs; p1.y = rotf<0x128>(hs);
            v2f arv = {0.f,0.f}, azv = {0.f,0.f};
            v2f axnv = {0.f,0.f}, ahnv = {0.f,0.f};
#pragma unroll
            for (int m = 0; m < 8; ++m) {
                arv  = __builtin_elementwise_fma(WIv[0][m],  p0, arv);
                arv  = __builtin_elementwise_fma(WHrv[0][m], p1, arv);
                azv  = __builtin_elementwise_fma(WIv[1][m],  p0, azv);
                azv  = __builtin_elementwise_fma(WHrv[1][m], p1, azv);
                axnv = __builtin_elementwise_fma(WIv[2][m],  p0, axnv);
                ahnv = __builtin_elementwise_fma(WHrv[2][m], p1, ahnv);
                if (m < 7) {
                    p0.x = rotf<0x121>(p0.x); p0.y = rotf<0x121>(p0.y);
                    p1.x = rotf<0x121>(p1.x); p1.y = rotf<0x121>(p1.y);
                }
            }
            const float r = fsigm(arv.x + arv.y + B_r);
            const float z = fsigm(azv.x + azv.y + B_z);
            const float n = ftanh(axnv.x + axnv.y + B_in
                                  + r * (ahnv.x + ahnv.y + B_hn));
            hs = fmaf(z, hs - n, n);
        };
        auto l1_xg = [&](float xa, float xh, int row) {   // f16 x-dot, fp32 out
            unsigned p = pk2(xa, xh);
            float ar = BX_r, az = BX_z, an = BX_n;
#pragma unroll
            for (int m = 0; m < 16; ++m) {
                ar = dot2(ar, WX[0][m], p);
                az = dot2(az, WX[1][m], p);
                an = dot2(an, WX[2][m], p);
                if (m < 15) p = rotu<0x121>(p);
            }
            const int par = (row >> 3) & 1, rb = row & 1;
            xgbuf[par][rb][0][bb][j] = ar;
            xgbuf[par][rb][1][bb][j] = az;
            xgbuf[par][rb][2][bb][j] = an;
        };

        // G = 0: no recurrence yet; produce xg rows 14,15; prefetch 22,23
        l1_xg(ya0, yh0, 14);
        l1_xg(ya1, yh1, 15);
        ya0 = xbase[22 * 32 + j];  yh0 = xbase[22 * 32 + 16 + j];
        ya1 = xbase[23 * 32 + j];  yh1 = xbase[23 * 32 + 16 + j];
        asm volatile("s_waitcnt lgkmcnt(0)\n\ts_barrier" ::: "memory");

#pragma unroll 1
        for (int G = 1; G < 64; ++G) {
            const int r0 = 8 * (G - 1);
            const int s0 = r0 & 15;
            const float u0 = h0buf[s0 + 0][bb][j];
            const float u1 = h0buf[s0 + 1][bb][j];
            const float u2 = h0buf[s0 + 2][bb][j];
            const float u3 = h0buf[s0 + 3][bb][j];
            const float u4 = h0buf[s0 + 4][bb][j];
            const float u5 = h0buf[s0 + 5][bb][j];
            const float u6 = h0buf[s0 + 6][bb][j];
            const float u7 = h0buf[s0 + 7][bb][j];
            l1_step(u0); l1_step(u1); l1_step(u2); l1_step(u3);
            l1_step(u4); l1_step(u5); l1_step(u6); l1_step(u7);
            if (G <= 62) {
                const int rx = 8 * (G + 1) + 6;
                l1_xg(ya0, yh0, rx);
                l1_xg(ya1, yh1, rx + 1);
                int pr = 8 * (G + 2) + 6;
                if (pr > T_LEN - 2) pr = T_LEN - 2;
                ya0 = xbase[pr * 32 + j];       yh0 = xbase[pr * 32 + 16 + j];
                ya1 = xbase[(pr + 1) * 32 + j]; yh1 = xbase[(pr + 1) * 32 + 16 + j];
            }
            asm volatile("s_waitcnt lgkmcnt(0)\n\ts_barrier" ::: "memory");
        }
        // G = 64: final recurrence group (rows 504..511, slots 8..15)
        {
            const int s0 = 8;
            const float u0 = h0buf[s0 + 0][bb][j];
            const float u1 = h0buf[s0 + 1][bb][j];
            const float u2 = h0buf[s0 + 2][bb][j];
            const float u3 = h0buf[s0 + 3][bb][j];
            const float u4 = h0buf[s0 + 4][bb][j];
            const float u5 = h0buf[s0 + 5][bb][j];
            const float u6 = h0buf[s0 + 6][bb][j];
            const float u7 = h0buf[s0 + 7][bb][j];
            l1_step(u0); l1_step(u1); l1_step(u2); l1_step(u3);
            l1_step(u4); l1_step(u5); l1_step(u6); l1_step(u7);
        }
        asm volatile("s_waitcnt lgkmcnt(0)\n\ts_barrier" ::: "memory");

        // FC on final h1 (distributed over j)
        float p = fcw[j] * hs;
        p += __shfl_xor(p, 1);
        p += __shfl_xor(p, 2);
        p += __shfl_xor(p, 4);
        p += __shfl_xor(p, 8);
        if (j == 0) out[b] = p + fcb[0];
    }
}

extern "C" void kernel_launch(void* const* d_in, const int* in_sizes, int n_in,
                              void* d_out, int out_size, void* d_ws, size_t ws_size,
                              hipStream_t stream) {
    const float* x    = (const float*)d_in[0];
    const float* Wih0 = (const float*)d_in[1];
    const float* Whh0 = (const float*)d_in[2];
    const float* bih0 = (const float*)d_in[3];
    const float* bhh0 = (const float*)d_in[4];
    const float* Wih1 = (const float*)d_in[5];
    const float* Whh1 = (const float*)d_in[6];
    const float* bih1 = (const float*)d_in[7];
    const float* bhh1 = (const float*)d_in[8];
    const float* fcw  = (const float*)d_in[9];
    const float* fcb  = (const float*)d_in[10];

    // 2048 batches, 8 per block -> 256 blocks x 256 threads
    gru2_mix<<<256, 256, 0, stream>>>(x, Wih0, Whh0, bih0, bhh0,
                                      Wih1, Whh1, bih1, bhh1, fcw, fcb,
                                      (float*)d_out);
}